// Round 8
// baseline (239.576 us; speedup 1.0000x reference)
//
#include <hip/hip_runtime.h>

// LIF neuron over [T, B, C, H, W] = [8, 32, 128, 32, 32] fp32.
// V_new = V + (-V/TAU + x_t); spike = (V_new>=1) - (V_new<=-1); hard reset.
//
// R1-R7 history: every source-level attempt at memory-level parallelism
// (hoist, asm fence, 4 independent columns) was re-serialized by the
// register-minimizing scheduler — VGPR_Count stayed 20-32, proving the
// loads were never concurrently live; perf pinned at 79-86 us / ~2.5 TB/s
// while the harness's own fills run 6.7 TB/s.
// R8: raw-asm loads. All 8 timestep loads are volatile inline-asm
// global_load_dwordx4 issued back-to-back (8 KB in flight per wave),
// followed by a manual s_waitcnt vmcnt(0) that data-ties all 8 results
// ("+v") so compute cannot be hoisted above it. The compiler cannot sink
// or serialize these. 4096 blocks -> 32 waves/CU -> ~256 KB in flight/CU.

#define T_STEPS 8

typedef float vfloat4 __attribute__((ext_vector_type(4)));

struct StepOut { float V; float o; };

__device__ __forceinline__ StepOut lif_step(float V, float x) {
    const float TAU = (float)(5.0 / 3.0);  // fp32, matches np cast
    // Replicate reference op order exactly: neg, IEEE divide, add, add.
    float dv = (-V) / TAU + x;
    float Vn = V + dv;
    float o = (Vn >= 1.0f ? 1.0f : 0.0f) - (Vn <= -1.0f ? 1.0f : 0.0f);
    StepOut r;
    r.o = o;
    r.V = (o == 0.0f) ? Vn : 0.0f;  // o is exactly -1/0/+1
    return r;
}

__device__ __forceinline__ vfloat4 lif_step4(vfloat4& V, vfloat4 xt) {
    StepOut a = lif_step(V.x, xt.x);
    StepOut b = lif_step(V.y, xt.y);
    StepOut c = lif_step(V.z, xt.z);
    StepOut d = lif_step(V.w, xt.w);
    vfloat4 Vn, o;
    Vn.x = a.V; Vn.y = b.V; Vn.z = c.V; Vn.w = d.V;
    o.x = a.o;  o.y = b.o;  o.z = c.o;  o.w = d.o;
    V = Vn;
    return o;
}

#define ASM_LOAD(dst, addr)                                        \
    asm volatile("global_load_dwordx4 %0, %1, off"                 \
                 : "=&v"(dst)                                      \
                 : "v"(addr))

__global__ __launch_bounds__(256) void lif_kernel(const float* __restrict__ x,
                                                  float* __restrict__ out,
                                                  int n4) {
    int i = blockIdx.x * blockDim.x + threadIdx.x;
    if (i >= n4) return;

    const unsigned long long stride = (unsigned long long)n4 * 16ull;  // bytes/timestep
    unsigned long long a = (unsigned long long)x + (unsigned long long)i * 16ull;

    vfloat4 x0, x1, x2, x3, x4, x5, x6, x7;
    // 8 back-to-back loads: volatile asm order is guaranteed, results land
    // in 32 VGPRs the compiler must keep live. 8 KB in flight per wave.
    ASM_LOAD(x0, a + 0 * stride);
    ASM_LOAD(x1, a + 1 * stride);
    ASM_LOAD(x2, a + 2 * stride);
    ASM_LOAD(x3, a + 3 * stride);
    ASM_LOAD(x4, a + 4 * stride);
    ASM_LOAD(x5, a + 5 * stride);
    ASM_LOAD(x6, a + 6 * stride);
    ASM_LOAD(x7, a + 7 * stride);
    // Manual drain; "+v" ties every loaded value to this asm so no use can
    // be scheduled above the wait.
    asm volatile("s_waitcnt vmcnt(0)"
                 : "+v"(x0), "+v"(x1), "+v"(x2), "+v"(x3),
                   "+v"(x4), "+v"(x5), "+v"(x6), "+v"(x7));

    const size_t s = (size_t)n4;
    vfloat4* o4 = (vfloat4*)out;
    vfloat4 V = (vfloat4)(0.f);
    o4[0 * s + i] = lif_step4(V, x0);
    o4[1 * s + i] = lif_step4(V, x1);
    o4[2 * s + i] = lif_step4(V, x2);
    o4[3 * s + i] = lif_step4(V, x3);
    o4[4 * s + i] = lif_step4(V, x4);
    o4[5 * s + i] = lif_step4(V, x5);
    o4[6 * s + i] = lif_step4(V, x6);
    o4[7 * s + i] = lif_step4(V, x7);
}

extern "C" void kernel_launch(void* const* d_in, const int* in_sizes, int n_in,
                              void* d_out, int out_size, void* d_ws, size_t ws_size,
                              hipStream_t stream) {
    const float* x = (const float*)d_in[0];
    float* out = (float*)d_out;

    int total = in_sizes[0];            // T*B*C*H*W = 33554432
    int n = total / T_STEPS;            // spatial elements per timestep
    int n4 = n / 4;                     // float4 groups = 1048576

    dim3 block(256);
    dim3 grid((n4 + block.x - 1) / block.x);  // 4096 blocks
    lif_kernel<<<grid, block, 0, stream>>>(x, out, n4);
}